// Round 4
// baseline (17696.338 us; speedup 1.0000x reference)
//
#include <hip/hip_runtime.h>

// ---------------------------------------------------------------------------
// StackedBidirectionalLstm  (B=32, T=512, IN=512, H=512, LAYERS=2, bidir, highway)
//
// Round 4: batch-split persistent recurrence. 8 independent groups
// (2 dir x 4 batch-quarters) x 16 WGs. No global barrier, no threadfence:
// h exchanged via L3-coherent AGENT-scope atomics; per-member flag words
// (no RMW contention). Weights in VGPRs (160/thread). px t-major, 64B spans.
//
//   ws layout (bytes), total ~202.1 MiB:
//     px   @ 0          201,326,592  ([2][512*32][3072] bf16, t-major)
//     whp  @ 201326592   10,485,760  (packed Wh fragments, 4 x 1,310,720 elems)
//     hbf  @ 211812352      131,072  (2 buf x 2 dir x 32 x 512 bf16)
//     flg  @ 211943424        4,096  ([2 layers][8 groups][16 members] u32)
//   d_out scratch:
//     phase A: xbf @ +0 (16 MiB), wxt0 @ +16 MiB (6 MiB), wxt1 @ +32 MiB (12 MiB)
//     phase B: a1bf @ +0 (32 MiB); layer-1 persist overwrites d_out with y.
// ---------------------------------------------------------------------------

typedef float f32x4 __attribute__((ext_vector_type(4)));
typedef __bf16 bf16x8 __attribute__((ext_vector_type(8)));
typedef unsigned short us8 __attribute__((ext_vector_type(8)));
typedef unsigned short us4 __attribute__((ext_vector_type(4)));
typedef unsigned long long u64x2 __attribute__((ext_vector_type(2)));

__device__ __forceinline__ unsigned short f2bf(float f) {
  unsigned int u = __float_as_uint(f);
  u += 0x7FFFu + ((u >> 16) & 1u);            // round-to-nearest-even
  return (unsigned short)(u >> 16);
}
__device__ __forceinline__ float bf2f(unsigned short h) {
  return __uint_as_float(((unsigned int)h) << 16);
}
__device__ __forceinline__ float sigf(float x) { return 1.0f / (1.0f + __expf(-x)); }
__device__ __forceinline__ float tanh_(float x) { return 2.0f / (1.0f + __expf(-2.0f * x)) - 1.0f; }

#define MFMA(a, b, c) __builtin_amdgcn_mfma_f32_16x16x32_bf16((a), (b), (c), 0, 0, 0)
#define GLOAD_LDS(gp, lp)                                                           \
  __builtin_amdgcn_global_load_lds(                                                 \
      (const __attribute__((address_space(1))) void*)(gp),                          \
      (__attribute__((address_space(3))) void*)(lp), 16, 0, 0)

// --------------------------- prep kernels ----------------------------------

__global__ void k_convert_x(const float* __restrict__ x, unsigned short* __restrict__ xb, int n4) {
  int i = blockIdx.x * blockDim.x + threadIdx.x;
  if (i < n4) {
    float4 v = ((const float4*)x)[i];
    us4 o;
    o[0] = f2bf(v.x); o[1] = f2bf(v.y); o[2] = f2bf(v.z); o[3] = f2bf(v.w);
    ((us4*)xb)[i] = o;
  }
}

// Tiled transpose: WxT[n][k] = bf16(Wx[k][n]); z = layer*2+dir
__global__ __launch_bounds__(256) void k_pack_wxT(
    const float* __restrict__ W0, const float* __restrict__ W1,
    const float* __restrict__ W2, const float* __restrict__ W3,
    unsigned short* __restrict__ o01, unsigned short* __restrict__ o23) {
  int y = blockIdx.z;
  int K = (y >> 1) ? 1024 : 512;
  int kb = blockIdx.y * 32;
  if (kb >= K) return;
  const float* W = (y == 0) ? W0 : (y == 1) ? W1 : (y == 2) ? W2 : W3;
  unsigned short* o = (y >> 1) ? (o23 + (size_t)(y & 1) * 3072 * 1024)
                               : (o01 + (size_t)(y & 1) * 3072 * 512);
  __shared__ float tile[32][33];
  int nb = blockIdx.x * 32;
  int tx = threadIdx.x & 31, ty = threadIdx.x >> 5;   // ty 0..7
#pragma unroll
  for (int r = 0; r < 4; ++r)
    tile[ty + r * 8][tx] = W[(size_t)(kb + ty + r * 8) * 3072 + nb + tx];
  __syncthreads();
#pragma unroll
  for (int r = 0; r < 4; ++r)
    o[(size_t)(nb + ty + r * 8) * K + kb + tx] = f2bf(tile[tx][ty + r * 8]);
}

// Pack Wh (512x2560 f32) into MFMA B-fragments:
// out[(((g*32+ns)*16+ks)*64+lane)*8+e] = Wh[ks*32+(lane>>4)*8+e][g*512+ns*16+(lane&15)]
__global__ void k_pack_whp(const float* __restrict__ W0, const float* __restrict__ W1,
                           const float* __restrict__ W2, const float* __restrict__ W3,
                           unsigned short* __restrict__ out) {
  int y = blockIdx.y;
  const float* W = (y == 0) ? W0 : (y == 1) ? W1 : (y == 2) ? W2 : W3;
  unsigned short* o = out + (size_t)y * 1310720;
  int v = blockIdx.x * 256 + threadIdx.x;   // < 163840
  int lane = v & 63, ks = (v >> 6) & 15, ns = (v >> 10) & 31, g = v >> 15;
  int col = g * 512 + ns * 16 + (lane & 15);
  int kb = ks * 32 + ((lane >> 4) << 3);
  us8 vec;
#pragma unroll
  for (int e = 0; e < 8; ++e) vec[e] = f2bf(W[(size_t)(kb + e) * 2560 + col]);
  *(us8*)&o[(size_t)v * 8] = vec;
}

// --------------------------- bf16 GEMM -------------------------------------
// px[rr][col] with rr = t*32+b (t-major), from A[16384][K] @ Bt[3072][K]^T.
__global__ __launch_bounds__(256) void k_gemm(const unsigned short* __restrict__ A,
                                              const unsigned short* __restrict__ BtBase,
                                              unsigned short* __restrict__ CBase, int K) {
  __shared__ __align__(128) unsigned short As[128 * 32];
  __shared__ __align__(128) unsigned short Bs[128 * 32];
  const unsigned short* Bt = BtBase + (size_t)blockIdx.z * 3072 * K;
  unsigned short* C = CBase + (size_t)blockIdx.z * 16384 * 3072;
  int tid = threadIdx.x;
  int w = tid >> 6, l = tid & 63;
  int m0 = blockIdx.x * 128, n0 = blockIdx.y * 128;
  int wr = (w >> 1) * 64, wc = (w & 1) * 64;
  f32x4 acc[4][4];
#pragma unroll
  for (int i = 0; i < 4; ++i)
#pragma unroll
    for (int j = 0; j < 4; ++j) acc[i][j] = (f32x4){0.f, 0.f, 0.f, 0.f};

  for (int k0 = 0; k0 < K; k0 += 32) {
    __syncthreads();
#pragma unroll
    for (int half = 0; half < 2; ++half) {
      int r = w * 32 + half * 16 + (l >> 2);     // row within tile
      int gq = (l & 3) ^ (r & 3);                // swizzled source quarter
      GLOAD_LDS(A + (size_t)(m0 + r) * K + k0 + gq * 8, &As[(w * 32 + half * 16) * 32]);
      GLOAD_LDS(Bt + (size_t)(n0 + r) * K + k0 + gq * 8, &Bs[(w * 32 + half * 16) * 32]);
    }
    __syncthreads();
    bf16x8 af[4], bfr[4];
#pragma unroll
    for (int mi = 0; mi < 4; ++mi) {
      int r = wr + mi * 16 + (l & 15);
      int q = (l >> 4) ^ (r & 3);
      af[mi] = __builtin_bit_cast(bf16x8, *(const us8*)&As[r * 32 + q * 8]);
    }
#pragma unroll
    for (int ni = 0; ni < 4; ++ni) {
      int r = wc + ni * 16 + (l & 15);
      int q = (l >> 4) ^ (r & 3);
      bfr[ni] = __builtin_bit_cast(bf16x8, *(const us8*)&Bs[r * 32 + q * 8]);
    }
#pragma unroll
    for (int mi = 0; mi < 4; ++mi)
#pragma unroll
      for (int ni = 0; ni < 4; ++ni) acc[mi][ni] = MFMA(af[mi], bfr[ni], acc[mi][ni]);
  }
#pragma unroll
  for (int mi = 0; mi < 4; ++mi)
#pragma unroll
    for (int ni = 0; ni < 4; ++ni)
#pragma unroll
      for (int r4 = 0; r4 < 4; ++r4) {
        int row = m0 + wr + mi * 16 + (l >> 4) * 4 + r4;    // b*512 + t
        int rr = ((row & 511) << 5) + (row >> 9);           // t*32 + b
        int col = n0 + wc + ni * 16 + (l & 15);
        C[(size_t)rr * 3072 + col] = f2bf(acc[mi][ni][r4]);
      }
}

// --------------------------- persistent LSTM layer -------------------------
// 128 WGs = 8 independent groups (dir d = grp&1, batch-quarter q = grp>>1)
// x 16 members. Member m covers hidden units m*32..m*32+31 (all 5 gates).
// Waves: w = kh*2+nh; nh = 16-hidden half, kh = 256-wide K half.
// h exchange + flags via AGENT-scope atomics (L3-coherent, no fences).
__global__ __launch_bounds__(256, 1) void k_persist(
    const unsigned short* __restrict__ px,    // [2][512*32][3072] bf16 t-major
    const unsigned short* __restrict__ wp,    // this layer's packed Wh (2 dirs)
    const float* __restrict__ bias_f, const float* __restrict__ bias_b,
    unsigned short* __restrict__ hx,          // [2 buf][2 dir][32][512] bf16
    unsigned short* __restrict__ ybf,         // layer0: a1bf, else null
    float* __restrict__ yf,                   // layer1: d_out, else null
    float* __restrict__ finals,               // d_out + 16777216
    unsigned int* __restrict__ flg, int layer) {
  __shared__ float part[4][8][80];            // 10 KiB partial ps
  __shared__ float hst[8][32];                // 1 KiB h staging
  int wg = blockIdx.x;
  int grp = wg >> 4, m = wg & 15;
  int d = grp & 1, q = grp >> 1;
  int tid = threadIdx.x;
  int w = tid >> 6, l = tid & 63;
  int kh = w >> 1, nh = w & 1;
  int ns = m * 2 + nh;                        // 16-hidden slice id (0..31)
  const unsigned short* wpd = wp + (size_t)d * 1310720;
  const unsigned short* pxd = px + (size_t)d * 16384 * 3072;
  const float* bias = d ? bias_b : bias_f;

  // ---- Wh fragments in VGPRs: wf[gate][kk] over this wave's K-half ----
  bf16x8 wf[5][8];
#pragma unroll
  for (int g5 = 0; g5 < 5; ++g5)
#pragma unroll
    for (int kk = 0; kk < 8; ++kk)
      wf[g5][kk] = __builtin_bit_cast(
          bf16x8,
          *(const us8*)&wpd[(size_t)((g5 * 32 + ns) * 16 + kh * 8 + kk) * 512 + l * 8]);

  // ---- epilogue constants: 1 output (row, hidden) per thread ----
  int r = tid >> 5, j = tid & 31, jg = m * 32 + j, b = q * 8 + r;
  float bv[5];
#pragma unroll
  for (int g5 = 0; g5 < 5; ++g5) bv[g5] = bias[(g5 << 9) + jg];

  float c = 0.f;
  unsigned short xv[6];
  {
    int t0 = d ? 511 : 0;
    const unsigned short* pp = pxd + ((size_t)((t0 << 5) + b)) * 3072 + jg;
#pragma unroll
    for (int q6 = 0; q6 < 6; ++q6) xv[q6] = pp[q6 << 9];
  }

  int lr = l & 15;                            // A-frag row (valid < 8)
  int hoff = (q * 8 + lr) * 512 + (kh << 8) + ((l >> 4) << 3);
  unsigned int* flgg = flg + ((layer << 3) + grp) * 16;
  unsigned long long* flgg64 = (unsigned long long*)flgg;

  for (int s = 0; s < 512; ++s) {
    int t = d ? (511 - s) : s;
    const unsigned short* hb = hx + (size_t)(((s & 1) << 1) + d) * 16384;

    // ---- coherent h loads (A fragments; rows 8..15 zero) ----
    unsigned long long hv[16];
    if (lr < 8) {
      const unsigned long long* hp = (const unsigned long long*)(hb + hoff);
#pragma unroll
      for (int kk = 0; kk < 8; ++kk) {
        hv[2 * kk] = __hip_atomic_load(hp + kk * 8, __ATOMIC_RELAXED,
                                       __HIP_MEMORY_SCOPE_AGENT);
        hv[2 * kk + 1] = __hip_atomic_load(hp + kk * 8 + 1, __ATOMIC_RELAXED,
                                           __HIP_MEMORY_SCOPE_AGENT);
      }
    } else {
#pragma unroll
      for (int i = 0; i < 16; ++i) hv[i] = 0ULL;
    }

    // ---- ps partial: M=8(pad16), 80 cols, K=256 per wave ----
    f32x4 acc[5];
#pragma unroll
    for (int g5 = 0; g5 < 5; ++g5) acc[g5] = (f32x4){0.f, 0.f, 0.f, 0.f};
#pragma unroll
    for (int kk = 0; kk < 8; ++kk) {
      u64x2 hpair = {hv[2 * kk], hv[2 * kk + 1]};
      bf16x8 a = __builtin_bit_cast(bf16x8, hpair);
#pragma unroll
      for (int g5 = 0; g5 < 5; ++g5) acc[g5] = MFMA(a, wf[g5][kk], acc[g5]);
    }
    if (l < 32) {
#pragma unroll
      for (int g5 = 0; g5 < 5; ++g5)
#pragma unroll
        for (int r4 = 0; r4 < 4; ++r4)
          part[w][(l >> 4) * 4 + r4][g5 * 16 + (l & 15)] = acc[g5][r4];
    }
    __syncthreads();

    // ---- gates / state (1 output per thread) ----
    {
      int nhe = j >> 4, jc = j & 15;
      float ps_[5];
#pragma unroll
      for (int g5 = 0; g5 < 5; ++g5) {
        int cc = g5 * 16 + jc;
        ps_[g5] = part[nhe][r][cc] + part[2 + nhe][r][cc] + bv[g5];
      }
      float x0 = bf2f(xv[0]), x1 = bf2f(xv[1]), x2 = bf2f(xv[2]);
      float x3 = bf2f(xv[3]), x4 = bf2f(xv[4]), x5 = bf2f(xv[5]);
      float iG = sigf(x0 + ps_[0]);
      float fG = sigf(x1 + ps_[1]);
      float gG = tanh_(x2 + ps_[2]);
      float oG = sigf(x3 + ps_[3]);
      float cn = iG * gG + fG * c;
      c = cn;
      float ht = oG * tanh_(cn);
      float rG = sigf(x4 + ps_[4]);
      ht = rG * ht + (1.f - rG) * x5;
      size_t yo = ((size_t)(b * 512 + t)) * 1024 + d * 512 + jg;
      if (ybf) ybf[yo] = f2bf(ht);
      else     yf[yo] = ht;
      if (s == 511) {
        int fo = (layer * 32 + b) * 1024 + d * 512 + jg;
        finals[fo] = ht;            // final_h
        finals[65536 + fo] = cn;    // final_c
      }
      hst[r][j] = ht;
    }
    __syncthreads();
    if (s == 511) break;

    // ---- publish h(t+1) slice (coherent u32 stores; no RMW) ----
    if (tid < 128) {
      int p0 = tid * 2;
      int r2 = p0 >> 5, j2 = p0 & 31;
      unsigned int v = (unsigned int)f2bf(hst[r2][j2]) |
                       ((unsigned int)f2bf(hst[r2][j2 + 1]) << 16);
      unsigned int* hq =
          (unsigned int*)(hx + (size_t)((((s + 1) & 1) << 1) + d) * 16384) +
          (((q * 8 + r2) * 512 + m * 32 + j2) >> 1);
      __hip_atomic_store(hq, v, __ATOMIC_RELAXED, __HIP_MEMORY_SCOPE_AGENT);
    }

    // ---- px prefetch for s+1 (overlaps store drain / poll) ----
    {
      int tn = d ? (511 - (s + 1)) : (s + 1);
      const unsigned short* pp = pxd + ((size_t)((tn << 5) + b)) * 3072 + jg;
#pragma unroll
      for (int q6 = 0; q6 < 6; ++q6) xv[q6] = pp[q6 << 9];
    }

    __syncthreads();   // drains vmem: h stores complete before flag release
    if (tid == 0) {
      __hip_atomic_store(&flgg[m], (unsigned int)(s + 1), __ATOMIC_RELEASE,
                         __HIP_MEMORY_SCOPE_AGENT);
      unsigned int tgt = (unsigned int)(s + 1);
      long guard = 0;
      bool ok;
      do {
        ok = true;
#pragma unroll
        for (int i = 0; i < 8; ++i) {
          unsigned long long f = __hip_atomic_load(
              &flgg64[i], __ATOMIC_ACQUIRE, __HIP_MEMORY_SCOPE_AGENT);
          ok = ok && ((unsigned int)f >= tgt) && ((unsigned int)(f >> 32) >= tgt);
        }
      } while (!ok && ++guard < 4000000L);
    }
    __syncthreads();
  }
}

// --------------------------- host ------------------------------------------

extern "C" void kernel_launch(void* const* d_in, const int* in_sizes, int n_in,
                              void* d_out, int out_size, void* d_ws, size_t ws_size,
                              hipStream_t stream) {
  (void)in_sizes; (void)n_in; (void)out_size; (void)ws_size;
  const float* x = (const float*)d_in[0];
  const float* Wx[4] = {(const float*)d_in[1], (const float*)d_in[4],
                        (const float*)d_in[7], (const float*)d_in[10]};
  const float* Wh[4] = {(const float*)d_in[2], (const float*)d_in[5],
                        (const float*)d_in[8], (const float*)d_in[11]};
  const float* bs[4] = {(const float*)d_in[3], (const float*)d_in[6],
                        (const float*)d_in[9], (const float*)d_in[12]};

  // ws: px + packed Wh + h double-buffer + flags (~202.1 MiB)
  char* ws = (char*)d_ws;
  unsigned short* px   = (unsigned short*)(ws);
  unsigned short* whp  = (unsigned short*)(ws + 201326592);
  unsigned short* hbf  = (unsigned short*)(ws + 211812352);
  unsigned int*   flg  = (unsigned int*)(ws + 211943424);

  // d_out doubles as scratch for transients (all dead before final y writes)
  char* ob = (char*)d_out;
  unsigned short* xbf  = (unsigned short*)(ob);             // 16 MiB, phase A
  unsigned short* wxt0 = (unsigned short*)(ob + 16777216);  // 6 MiB, phase A
  unsigned short* wxt1 = (unsigned short*)(ob + 33554432);  // 12 MiB
  unsigned short* a1bf = (unsigned short*)(ob);             // 32 MiB, phase B
  float* out = (float*)d_out;
  float* finals = out + 16777216;

  k_convert_x<<<8192, 256, 0, stream>>>(x, xbf, 2097152);
  k_pack_wxT<<<dim3(96, 32, 4), 256, 0, stream>>>(Wx[0], Wx[1], Wx[2], Wx[3], wxt0, wxt1);
  k_pack_whp<<<dim3(640, 4), 256, 0, stream>>>(Wh[0], Wh[1], Wh[2], Wh[3], whp);
  hipMemsetAsync(flg, 0, 4096, stream);

  for (int layer = 0; layer < 2; ++layer) {
    int K = layer ? 1024 : 512;
    const unsigned short* Ag = layer ? a1bf : xbf;
    const unsigned short* wxt = layer ? wxt1 : wxt0;
    k_gemm<<<dim3(128, 24, 2), 256, 0, stream>>>(Ag, wxt, px, K);
    hipMemsetAsync(hbf, 0, 131072, stream);   // zero both h double-buffers
    k_persist<<<128, 256, 0, stream>>>(
        px, whp + (size_t)layer * 2621440, bs[layer * 2], bs[layer * 2 + 1],
        hbf, layer ? nullptr : a1bf, layer ? out : nullptr, finals, flg, layer);
  }
}

// Round 5
// 4569.403 us; speedup vs baseline: 3.8728x; 3.8728x over previous
//
#include <hip/hip_runtime.h>

// ---------------------------------------------------------------------------
// StackedBidirectionalLstm  (B=32, T=512, IN=512, H=512, LAYERS=2, bidir, highway)
//
// Round 5: same batch-split persistent structure as round 4 (8 independent
// groups = 2 dir x 4 batch-quarters, 16 WGs each; weights in regs), but ALL
// cross-WG sync via hand-written sc0/sc1 cache-bypass loads/stores (inline
// asm). No __hip_atomic acquire/release => no buffer_inv / buffer_wbl2 storms.
//
//   ws layout (bytes), total ~202.1 MiB:
//     px   @ 0          201,326,592  ([2][512*32][3072] bf16, t-major)
//     whp  @ 201326592   10,485,760  (packed Wh fragments, 4 x 1,310,720 elems)
//     hbf  @ 211812352      131,072  (2 buf x 2 dir x 32 x 512 bf16)
//     flg  @ 211943424        4,096  ([2 layers][8 groups][16 members] u32)
//   d_out scratch:
//     phase A: xbf @ +0 (16 MiB), wxt0 @ +16 MiB (6 MiB), wxt1 @ +32 MiB (12 MiB)
//     phase B: a1bf @ +0 (32 MiB); layer-1 persist overwrites d_out with y.
// ---------------------------------------------------------------------------

typedef float f32x4 __attribute__((ext_vector_type(4)));
typedef __bf16 bf16x8 __attribute__((ext_vector_type(8)));
typedef unsigned short us8 __attribute__((ext_vector_type(8)));
typedef unsigned short us4 __attribute__((ext_vector_type(4)));
typedef unsigned int u32x4 __attribute__((ext_vector_type(4)));

__device__ __forceinline__ unsigned short f2bf(float f) {
  unsigned int u = __float_as_uint(f);
  u += 0x7FFFu + ((u >> 16) & 1u);            // round-to-nearest-even
  return (unsigned short)(u >> 16);
}
__device__ __forceinline__ float bf2f(unsigned short h) {
  return __uint_as_float(((unsigned int)h) << 16);
}
__device__ __forceinline__ float sigf(float x) { return 1.0f / (1.0f + __expf(-x)); }
__device__ __forceinline__ float tanh_(float x) { return 2.0f / (1.0f + __expf(-2.0f * x)) - 1.0f; }

#define MFMA(a, b, c) __builtin_amdgcn_mfma_f32_16x16x32_bf16((a), (b), (c), 0, 0, 0)
#define GLOAD_LDS(gp, lp)                                                           \
  __builtin_amdgcn_global_load_lds(                                                 \
      (const __attribute__((address_space(1))) void*)(gp),                          \
      (__attribute__((address_space(3))) void*)(lp), 16, 0, 0)

// ---- sc0/sc1 cache-bypass primitives (no cache-maintenance side effects) ----

// 8 x 16B coherent loads (consecutive 64B-strided chunks) + one vmcnt(0).
__device__ __forceinline__ void hload8(const unsigned short* base, u32x4 h[8]) {
  asm volatile(
      "global_load_dwordx4 %0, %8, off sc0 sc1\n\t"
      "global_load_dwordx4 %1, %8, off offset:64 sc0 sc1\n\t"
      "global_load_dwordx4 %2, %8, off offset:128 sc0 sc1\n\t"
      "global_load_dwordx4 %3, %8, off offset:192 sc0 sc1\n\t"
      "global_load_dwordx4 %4, %8, off offset:256 sc0 sc1\n\t"
      "global_load_dwordx4 %5, %8, off offset:320 sc0 sc1\n\t"
      "global_load_dwordx4 %6, %8, off offset:384 sc0 sc1\n\t"
      "global_load_dwordx4 %7, %8, off offset:448 sc0 sc1\n\t"
      "s_waitcnt vmcnt(0)"
      : "=&v"(h[0]), "=&v"(h[1]), "=&v"(h[2]), "=&v"(h[3]),
        "=&v"(h[4]), "=&v"(h[5]), "=&v"(h[6]), "=&v"(h[7])
      : "v"(base)
      : "memory");
}

__device__ __forceinline__ void hstore16(unsigned short* p, u32x4 v) {
  asm volatile("global_store_dwordx4 %0, %1, off sc0 sc1" :: "v"(p), "v"(v) : "memory");
}

// Wait for this wave's outstanding vmem (h publish) then release the flag.
__device__ __forceinline__ void flag_release(unsigned int* p, unsigned int v) {
  asm volatile("s_waitcnt vmcnt(0)\n\t"
               "global_store_dword %0, %1, off sc0 sc1" :: "v"(p), "v"(v) : "memory");
}

// Relaxed coherent read of 16 flag words (one 64B line) + vmcnt(0).
__device__ __forceinline__ void flag_load(const unsigned int* p, u32x4 f[4]) {
  asm volatile(
      "global_load_dwordx4 %0, %4, off sc0 sc1\n\t"
      "global_load_dwordx4 %1, %4, off offset:16 sc0 sc1\n\t"
      "global_load_dwordx4 %2, %4, off offset:32 sc0 sc1\n\t"
      "global_load_dwordx4 %3, %4, off offset:48 sc0 sc1\n\t"
      "s_waitcnt vmcnt(0)"
      : "=&v"(f[0]), "=&v"(f[1]), "=&v"(f[2]), "=&v"(f[3])
      : "v"(p)
      : "memory");
}

// --------------------------- prep kernels ----------------------------------

__global__ void k_convert_x(const float* __restrict__ x, unsigned short* __restrict__ xb, int n4) {
  int i = blockIdx.x * blockDim.x + threadIdx.x;
  if (i < n4) {
    float4 v = ((const float4*)x)[i];
    us4 o;
    o[0] = f2bf(v.x); o[1] = f2bf(v.y); o[2] = f2bf(v.z); o[3] = f2bf(v.w);
    ((us4*)xb)[i] = o;
  }
}

// Tiled transpose: WxT[n][k] = bf16(Wx[k][n]); z = layer*2+dir
__global__ __launch_bounds__(256) void k_pack_wxT(
    const float* __restrict__ W0, const float* __restrict__ W1,
    const float* __restrict__ W2, const float* __restrict__ W3,
    unsigned short* __restrict__ o01, unsigned short* __restrict__ o23) {
  int y = blockIdx.z;
  int K = (y >> 1) ? 1024 : 512;
  int kb = blockIdx.y * 32;
  if (kb >= K) return;
  const float* W = (y == 0) ? W0 : (y == 1) ? W1 : (y == 2) ? W2 : W3;
  unsigned short* o = (y >> 1) ? (o23 + (size_t)(y & 1) * 3072 * 1024)
                               : (o01 + (size_t)(y & 1) * 3072 * 512);
  __shared__ float tile[32][33];
  int nb = blockIdx.x * 32;
  int tx = threadIdx.x & 31, ty = threadIdx.x >> 5;   // ty 0..7
#pragma unroll
  for (int r = 0; r < 4; ++r)
    tile[ty + r * 8][tx] = W[(size_t)(kb + ty + r * 8) * 3072 + nb + tx];
  __syncthreads();
#pragma unroll
  for (int r = 0; r < 4; ++r)
    o[(size_t)(nb + ty + r * 8) * K + kb + tx] = f2bf(tile[tx][ty + r * 8]);
}

// Pack Wh (512x2560 f32) into MFMA B-fragments:
// out[(((g*32+ns)*16+ks)*64+lane)*8+e] = Wh[ks*32+(lane>>4)*8+e][g*512+ns*16+(lane&15)]
__global__ void k_pack_whp(const float* __restrict__ W0, const float* __restrict__ W1,
                           const float* __restrict__ W2, const float* __restrict__ W3,
                           unsigned short* __restrict__ out) {
  int y = blockIdx.y;
  const float* W = (y == 0) ? W0 : (y == 1) ? W1 : (y == 2) ? W2 : W3;
  unsigned short* o = out + (size_t)y * 1310720;
  int v = blockIdx.x * 256 + threadIdx.x;   // < 163840
  int lane = v & 63, ks = (v >> 6) & 15, ns = (v >> 10) & 31, g = v >> 15;
  int col = g * 512 + ns * 16 + (lane & 15);
  int kb = ks * 32 + ((lane >> 4) << 3);
  us8 vec;
#pragma unroll
  for (int e = 0; e < 8; ++e) vec[e] = f2bf(W[(size_t)(kb + e) * 2560 + col]);
  *(us8*)&o[(size_t)v * 8] = vec;
}

// --------------------------- bf16 GEMM -------------------------------------
// px[rr][col] with rr = t*32+b (t-major), from A[16384][K] @ Bt[3072][K]^T.
__global__ __launch_bounds__(256) void k_gemm(const unsigned short* __restrict__ A,
                                              const unsigned short* __restrict__ BtBase,
                                              unsigned short* __restrict__ CBase, int K) {
  __shared__ __align__(128) unsigned short As[128 * 32];
  __shared__ __align__(128) unsigned short Bs[128 * 32];
  const unsigned short* Bt = BtBase + (size_t)blockIdx.z * 3072 * K;
  unsigned short* C = CBase + (size_t)blockIdx.z * 16384 * 3072;
  int tid = threadIdx.x;
  int w = tid >> 6, l = tid & 63;
  int m0 = blockIdx.x * 128, n0 = blockIdx.y * 128;
  int wr = (w >> 1) * 64, wc = (w & 1) * 64;
  f32x4 acc[4][4];
#pragma unroll
  for (int i = 0; i < 4; ++i)
#pragma unroll
    for (int j = 0; j < 4; ++j) acc[i][j] = (f32x4){0.f, 0.f, 0.f, 0.f};

  for (int k0 = 0; k0 < K; k0 += 32) {
    __syncthreads();
#pragma unroll
    for (int half = 0; half < 2; ++half) {
      int r = w * 32 + half * 16 + (l >> 2);     // row within tile
      int gq = (l & 3) ^ (r & 3);                // swizzled source quarter
      GLOAD_LDS(A + (size_t)(m0 + r) * K + k0 + gq * 8, &As[(w * 32 + half * 16) * 32]);
      GLOAD_LDS(Bt + (size_t)(n0 + r) * K + k0 + gq * 8, &Bs[(w * 32 + half * 16) * 32]);
    }
    __syncthreads();
    bf16x8 af[4], bfr[4];
#pragma unroll
    for (int mi = 0; mi < 4; ++mi) {
      int r = wr + mi * 16 + (l & 15);
      int q = (l >> 4) ^ (r & 3);
      af[mi] = __builtin_bit_cast(bf16x8, *(const us8*)&As[r * 32 + q * 8]);
    }
#pragma unroll
    for (int ni = 0; ni < 4; ++ni) {
      int r = wc + ni * 16 + (l & 15);
      int q = (l >> 4) ^ (r & 3);
      bfr[ni] = __builtin_bit_cast(bf16x8, *(const us8*)&Bs[r * 32 + q * 8]);
    }
#pragma unroll
    for (int mi = 0; mi < 4; ++mi)
#pragma unroll
      for (int ni = 0; ni < 4; ++ni) acc[mi][ni] = MFMA(af[mi], bfr[ni], acc[mi][ni]);
  }
#pragma unroll
  for (int mi = 0; mi < 4; ++mi)
#pragma unroll
    for (int ni = 0; ni < 4; ++ni)
#pragma unroll
      for (int r4 = 0; r4 < 4; ++r4) {
        int row = m0 + wr + mi * 16 + (l >> 4) * 4 + r4;    // b*512 + t
        int rr = ((row & 511) << 5) + (row >> 9);           // t*32 + b
        int col = n0 + wc + ni * 16 + (l & 15);
        C[(size_t)rr * 3072 + col] = f2bf(acc[mi][ni][r4]);
      }
}

// --------------------------- persistent LSTM layer -------------------------
// 128 WGs = 8 independent groups (dir d = grp&1, batch-quarter q = grp>>1)
// x 16 members. Member m covers hidden units m*32..m*32+31 (all 5 gates).
// Waves: w = kh*2+nh; nh = 16-hidden half, kh = 256-wide K half.
// h exchange + flags via asm sc0/sc1 (cache-bypass, no wbinv ops).
__global__ __launch_bounds__(256, 1) void k_persist(
    const unsigned short* __restrict__ px,    // [2][512*32][3072] bf16 t-major
    const unsigned short* __restrict__ wp,    // this layer's packed Wh (2 dirs)
    const float* __restrict__ bias_f, const float* __restrict__ bias_b,
    unsigned short* __restrict__ hx,          // [2 buf][2 dir][32][512] bf16
    unsigned short* __restrict__ ybf,         // layer0: a1bf, else null
    float* __restrict__ yf,                   // layer1: d_out, else null
    float* __restrict__ finals,               // d_out + 16777216
    unsigned int* __restrict__ flg, int layer) {
  __shared__ float part[4][8][80];            // 10 KiB partial ps
  __shared__ float hst[8][32];                // 1 KiB h staging
  int wg = blockIdx.x;
  int grp = wg >> 4, m = wg & 15;
  int d = grp & 1, q = grp >> 1;
  int tid = threadIdx.x;
  int w = tid >> 6, l = tid & 63;
  int kh = w >> 1, nh = w & 1;
  int ns = m * 2 + nh;                        // 16-hidden slice id (0..31)
  const unsigned short* wpd = wp + (size_t)d * 1310720;
  const unsigned short* pxd = px + (size_t)d * 16384 * 3072;
  const float* bias = d ? bias_b : bias_f;

  // ---- Wh fragments in regs: wf[gate][kk] over this wave's K-half ----
  bf16x8 wf[5][8];
#pragma unroll
  for (int g5 = 0; g5 < 5; ++g5)
#pragma unroll
    for (int kk = 0; kk < 8; ++kk)
      wf[g5][kk] = __builtin_bit_cast(
          bf16x8,
          *(const us8*)&wpd[(size_t)((g5 * 32 + ns) * 16 + kh * 8 + kk) * 512 + l * 8]);

  // ---- epilogue constants: 1 output (row, hidden) per thread ----
  int r = tid >> 5, j = tid & 31, jg = m * 32 + j, b = q * 8 + r;
  float bv[5];
#pragma unroll
  for (int g5 = 0; g5 < 5; ++g5) bv[g5] = bias[(g5 << 9) + jg];

  float c = 0.f;
  unsigned short xv[6];
  {
    int t0 = d ? 511 : 0;
    const unsigned short* pp = pxd + ((size_t)((t0 << 5) + b)) * 3072 + jg;
#pragma unroll
    for (int q6 = 0; q6 < 6; ++q6) xv[q6] = pp[q6 << 9];
  }

  int lr = l & 15;
  // A-frag source row (clamped for the padded rows 8..15 -> garbage, discarded)
  int hoff = (q * 8 + (lr & 7)) * 512 + (kh << 8) + ((l >> 4) << 3);
  unsigned int* flgg = flg + ((layer << 3) + grp) * 16;

  for (int s = 0; s < 512; ++s) {
    int t = d ? (511 - s) : s;
    const unsigned short* hb = hx + (size_t)(((s & 1) << 1) + d) * 16384;

    // ---- coherent h loads: 8 x dwordx4 (sc0 sc1) ----
    u32x4 hc[8];
    hload8(hb + hoff, hc);

    // ---- ps partial: M=8(pad16), 80 cols, K=256 per wave ----
    f32x4 acc[5];
#pragma unroll
    for (int g5 = 0; g5 < 5; ++g5) acc[g5] = (f32x4){0.f, 0.f, 0.f, 0.f};
#pragma unroll
    for (int kk = 0; kk < 8; ++kk) {
      bf16x8 a = __builtin_bit_cast(bf16x8, hc[kk]);
#pragma unroll
      for (int g5 = 0; g5 < 5; ++g5) acc[g5] = MFMA(a, wf[g5][kk], acc[g5]);
    }
    if (l < 32) {
#pragma unroll
      for (int g5 = 0; g5 < 5; ++g5)
#pragma unroll
        for (int r4 = 0; r4 < 4; ++r4)
          part[w][(l >> 4) * 4 + r4][g5 * 16 + (l & 15)] = acc[g5][r4];
    }
    __syncthreads();

    // ---- gates / state (1 output per thread) ----
    {
      int nhe = j >> 4, jc = j & 15;
      float ps_[5];
#pragma unroll
      for (int g5 = 0; g5 < 5; ++g5) {
        int cc = g5 * 16 + jc;
        ps_[g5] = part[nhe][r][cc] + part[2 + nhe][r][cc] + bv[g5];
      }
      float x0 = bf2f(xv[0]), x1 = bf2f(xv[1]), x2 = bf2f(xv[2]);
      float x3 = bf2f(xv[3]), x4 = bf2f(xv[4]), x5 = bf2f(xv[5]);
      float iG = sigf(x0 + ps_[0]);
      float fG = sigf(x1 + ps_[1]);
      float gG = tanh_(x2 + ps_[2]);
      float oG = sigf(x3 + ps_[3]);
      float cn = iG * gG + fG * c;
      c = cn;
      float ht = oG * tanh_(cn);
      float rG = sigf(x4 + ps_[4]);
      ht = rG * ht + (1.f - rG) * x5;
      size_t yo = ((size_t)(b * 512 + t)) * 1024 + d * 512 + jg;
      if (ybf) ybf[yo] = f2bf(ht);
      else     yf[yo] = ht;
      if (s == 511) {
        int fo = (layer * 32 + b) * 1024 + d * 512 + jg;
        finals[fo] = ht;            // final_h
        finals[65536 + fo] = cn;    // final_c
      }
      hst[r][j] = ht;
    }
    __syncthreads();
    if (s == 511) break;

    // ---- px prefetch for s+1 (all waves; latency hides under sync) ----
    {
      int tn = d ? (511 - (s + 1)) : (s + 1);
      const unsigned short* pp = pxd + ((size_t)((tn << 5) + b)) * 3072 + jg;
#pragma unroll
      for (int q6 = 0; q6 < 6; ++q6) xv[q6] = pp[q6 << 9];
    }

    // ---- publish h(t+1) slice + flag release + poll (wave 0 only) ----
    if (w == 0) {
      unsigned short* hn = hx + (size_t)((((s + 1) & 1) << 1) + d) * 16384;
      if (l < 32) {
        int r2 = l >> 2, ch = l & 3;
        u32x4 pv;
#pragma unroll
        for (int e = 0; e < 4; ++e) {
          unsigned int lo = f2bf(hst[r2][ch * 8 + 2 * e]);
          unsigned int hi = f2bf(hst[r2][ch * 8 + 2 * e + 1]);
          pv[e] = lo | (hi << 16);
        }
        hstore16(hn + (q * 8 + r2) * 512 + m * 32 + ch * 8, pv);
      }
      if (l == 0) {
        unsigned int tgt = (unsigned int)(s + 1);
        flag_release(&flgg[m], tgt);         // vmcnt(0) then sc-bypass store
        long guard = 0;
        bool ok;
        do {
          u32x4 f4[4];
          flag_load(flgg, f4);
          unsigned int mn = 0xFFFFFFFFu;
#pragma unroll
          for (int i = 0; i < 4; ++i)
#pragma unroll
            for (int e = 0; e < 4; ++e) mn = min(mn, f4[i][e]);
          ok = (mn >= tgt);
        } while (!ok && ++guard < 1000000L);
      }
    }
    __syncthreads();
  }
}

// --------------------------- host ------------------------------------------

extern "C" void kernel_launch(void* const* d_in, const int* in_sizes, int n_in,
                              void* d_out, int out_size, void* d_ws, size_t ws_size,
                              hipStream_t stream) {
  (void)in_sizes; (void)n_in; (void)out_size; (void)ws_size;
  const float* x = (const float*)d_in[0];
  const float* Wx[4] = {(const float*)d_in[1], (const float*)d_in[4],
                        (const float*)d_in[7], (const float*)d_in[10]};
  const float* Wh[4] = {(const float*)d_in[2], (const float*)d_in[5],
                        (const float*)d_in[8], (const float*)d_in[11]};
  const float* bs[4] = {(const float*)d_in[3], (const float*)d_in[6],
                        (const float*)d_in[9], (const float*)d_in[12]};

  // ws: px + packed Wh + h double-buffer + flags (~202.1 MiB)
  char* ws = (char*)d_ws;
  unsigned short* px   = (unsigned short*)(ws);
  unsigned short* whp  = (unsigned short*)(ws + 201326592);
  unsigned short* hbf  = (unsigned short*)(ws + 211812352);
  unsigned int*   flg  = (unsigned int*)(ws + 211943424);

  // d_out doubles as scratch for transients (all dead before final y writes)
  char* ob = (char*)d_out;
  unsigned short* xbf  = (unsigned short*)(ob);             // 16 MiB, phase A
  unsigned short* wxt0 = (unsigned short*)(ob + 16777216);  // 6 MiB, phase A
  unsigned short* wxt1 = (unsigned short*)(ob + 33554432);  // 12 MiB
  unsigned short* a1bf = (unsigned short*)(ob);             // 32 MiB, phase B
  float* out = (float*)d_out;
  float* finals = out + 16777216;

  k_convert_x<<<8192, 256, 0, stream>>>(x, xbf, 2097152);
  k_pack_wxT<<<dim3(96, 32, 4), 256, 0, stream>>>(Wx[0], Wx[1], Wx[2], Wx[3], wxt0, wxt1);
  k_pack_whp<<<dim3(640, 4), 256, 0, stream>>>(Wh[0], Wh[1], Wh[2], Wh[3], whp);
  hipMemsetAsync(flg, 0, 4096, stream);

  for (int layer = 0; layer < 2; ++layer) {
    int K = layer ? 1024 : 512;
    const unsigned short* Ag = layer ? a1bf : xbf;
    const unsigned short* wxt = layer ? wxt1 : wxt0;
    k_gemm<<<dim3(128, 24, 2), 256, 0, stream>>>(Ag, wxt, px, K);
    hipMemsetAsync(hbf, 0, 131072, stream);   // zero both h double-buffers
    k_persist<<<128, 256, 0, stream>>>(
        px, whp + (size_t)layer * 2621440, bs[layer * 2], bs[layer * 2 + 1],
        hbf, layer ? nullptr : a1bf, layer ? out : nullptr, finals, flg, layer);
  }
}

// Round 6
// 3111.216 us; speedup vs baseline: 5.6879x; 1.4687x over previous
//
#include <hip/hip_runtime.h>

// ---------------------------------------------------------------------------
// StackedBidirectionalLstm  (B=32, T=512, IN=512, H=512, LAYERS=2, bidir, highway)
//
// Round 6: 1-RTT h exchange. 8 independent groups (2 dir x 4 batch-quarters)
// x 16 member WGs. h published as 16B atomic chunks {6 bf16 | seq}: data and
// flag travel together (single-copy atomic dwordx4), so no producer ack, no
// separate flag poll. Consumers poll the chunks; seq==s validates payload.
// Weights stationary in regs. px t-major. 2 barriers/step, publish early.
//
//   ws layout (bytes):
//     px   @ 0          201,326,592  ([2][512*32][3072] bf16, t-major)
//     whp  @ 201326592   10,485,760  (packed Wh fragments)
//     hxc  @ 211812352      196,608  ([2 buf][8 grp][16 m][8 row][6 ch] x 16B)
//   d_out scratch:
//     phase A: xbf @ +0 (16 MiB), wxt0 @ +16 MiB (6 MiB), wxt1 @ +32 MiB (12 MiB)
//     phase B: a1bf @ +0 (32 MiB); layer-1 persist overwrites d_out with y.
// ---------------------------------------------------------------------------

typedef float f32x4 __attribute__((ext_vector_type(4)));
typedef __bf16 bf16x8 __attribute__((ext_vector_type(8)));
typedef unsigned short us8 __attribute__((ext_vector_type(8)));
typedef unsigned short us4 __attribute__((ext_vector_type(4)));
typedef unsigned int u32x4 __attribute__((ext_vector_type(4)));

__device__ __forceinline__ unsigned short f2bf(float f) {
  unsigned int u = __float_as_uint(f);
  u += 0x7FFFu + ((u >> 16) & 1u);            // round-to-nearest-even
  return (unsigned short)(u >> 16);
}
__device__ __forceinline__ float bf2f(unsigned short h) {
  return __uint_as_float(((unsigned int)h) << 16);
}
__device__ __forceinline__ float sigf(float x) { return 1.0f / (1.0f + __expf(-x)); }
__device__ __forceinline__ float tanh_(float x) { return 2.0f / (1.0f + __expf(-2.0f * x)) - 1.0f; }

#define MFMA(a, b, c) __builtin_amdgcn_mfma_f32_16x16x32_bf16((a), (b), (c), 0, 0, 0)
#define GLOAD_LDS(gp, lp)                                                           \
  __builtin_amdgcn_global_load_lds(                                                 \
      (const __attribute__((address_space(1))) void*)(gp),                          \
      (__attribute__((address_space(3))) void*)(lp), 16, 0, 0)

// Two coherent 16B chunk loads (L1/L2 bypass); NO waitcnt inside.
__device__ __forceinline__ void chunk2_load(const char* p, u32x4& a, u32x4& b) {
  asm volatile(
      "global_load_dwordx4 %0, %2, off sc0 sc1\n\t"
      "global_load_dwordx4 %1, %2, off offset:16 sc0 sc1"
      : "=&v"(a), "=&v"(b) : "v"(p) : "memory");
}
__device__ __forceinline__ void hstore16(char* p, u32x4 v) {
  asm volatile("global_store_dwordx4 %0, %1, off sc0 sc1" :: "v"(p), "v"(v) : "memory");
}

// --------------------------- prep kernels ----------------------------------

__global__ void k_convert_x(const float* __restrict__ x, unsigned short* __restrict__ xb, int n4) {
  int i = blockIdx.x * blockDim.x + threadIdx.x;
  if (i < n4) {
    float4 v = ((const float4*)x)[i];
    us4 o;
    o[0] = f2bf(v.x); o[1] = f2bf(v.y); o[2] = f2bf(v.z); o[3] = f2bf(v.w);
    ((us4*)xb)[i] = o;
  }
}

// Tiled transpose: WxT[n][k] = bf16(Wx[k][n]); z = layer*2+dir
__global__ __launch_bounds__(256) void k_pack_wxT(
    const float* __restrict__ W0, const float* __restrict__ W1,
    const float* __restrict__ W2, const float* __restrict__ W3,
    unsigned short* __restrict__ o01, unsigned short* __restrict__ o23) {
  int y = blockIdx.z;
  int K = (y >> 1) ? 1024 : 512;
  int kb = blockIdx.y * 32;
  if (kb >= K) return;
  const float* W = (y == 0) ? W0 : (y == 1) ? W1 : (y == 2) ? W2 : W3;
  unsigned short* o = (y >> 1) ? (o23 + (size_t)(y & 1) * 3072 * 1024)
                               : (o01 + (size_t)(y & 1) * 3072 * 512);
  __shared__ float tile[32][33];
  int nb = blockIdx.x * 32;
  int tx = threadIdx.x & 31, ty = threadIdx.x >> 5;   // ty 0..7
#pragma unroll
  for (int r = 0; r < 4; ++r)
    tile[ty + r * 8][tx] = W[(size_t)(kb + ty + r * 8) * 3072 + nb + tx];
  __syncthreads();
#pragma unroll
  for (int r = 0; r < 4; ++r)
    o[(size_t)(nb + ty + r * 8) * K + kb + tx] = f2bf(tile[tx][ty + r * 8]);
}

// Pack Wh (512x2560 f32) into MFMA B-fragments:
// out[(((g*32+ns)*16+ks)*64+lane)*8+e] = Wh[ks*32+(lane>>4)*8+e][g*512+ns*16+(lane&15)]
__global__ void k_pack_whp(const float* __restrict__ W0, const float* __restrict__ W1,
                           const float* __restrict__ W2, const float* __restrict__ W3,
                           unsigned short* __restrict__ out) {
  int y = blockIdx.y;
  const float* W = (y == 0) ? W0 : (y == 1) ? W1 : (y == 2) ? W2 : W3;
  unsigned short* o = out + (size_t)y * 1310720;
  int v = blockIdx.x * 256 + threadIdx.x;   // < 163840
  int lane = v & 63, ks = (v >> 6) & 15, ns = (v >> 10) & 31, g = v >> 15;
  int col = g * 512 + ns * 16 + (lane & 15);
  int kb = ks * 32 + ((lane >> 4) << 3);
  us8 vec;
#pragma unroll
  for (int e = 0; e < 8; ++e) vec[e] = f2bf(W[(size_t)(kb + e) * 2560 + col]);
  *(us8*)&o[(size_t)v * 8] = vec;
}

// --------------------------- bf16 GEMM -------------------------------------
// px[rr][col] with rr = t*32+b (t-major), from A[16384][K] @ Bt[3072][K]^T.
__global__ __launch_bounds__(256) void k_gemm(const unsigned short* __restrict__ A,
                                              const unsigned short* __restrict__ BtBase,
                                              unsigned short* __restrict__ CBase, int K) {
  __shared__ __align__(128) unsigned short As[128 * 32];
  __shared__ __align__(128) unsigned short Bs[128 * 32];
  const unsigned short* Bt = BtBase + (size_t)blockIdx.z * 3072 * K;
  unsigned short* C = CBase + (size_t)blockIdx.z * 16384 * 3072;
  int tid = threadIdx.x;
  int w = tid >> 6, l = tid & 63;
  int m0 = blockIdx.x * 128, n0 = blockIdx.y * 128;
  int wr = (w >> 1) * 64, wc = (w & 1) * 64;
  f32x4 acc[4][4];
#pragma unroll
  for (int i = 0; i < 4; ++i)
#pragma unroll
    for (int j = 0; j < 4; ++j) acc[i][j] = (f32x4){0.f, 0.f, 0.f, 0.f};

  for (int k0 = 0; k0 < K; k0 += 32) {
    __syncthreads();
#pragma unroll
    for (int half = 0; half < 2; ++half) {
      int r = w * 32 + half * 16 + (l >> 2);     // row within tile
      int gq = (l & 3) ^ (r & 3);                // swizzled source quarter
      GLOAD_LDS(A + (size_t)(m0 + r) * K + k0 + gq * 8, &As[(w * 32 + half * 16) * 32]);
      GLOAD_LDS(Bt + (size_t)(n0 + r) * K + k0 + gq * 8, &Bs[(w * 32 + half * 16) * 32]);
    }
    __syncthreads();
    bf16x8 af[4], bfr[4];
#pragma unroll
    for (int mi = 0; mi < 4; ++mi) {
      int r = wr + mi * 16 + (l & 15);
      int q = (l >> 4) ^ (r & 3);
      af[mi] = __builtin_bit_cast(bf16x8, *(const us8*)&As[r * 32 + q * 8]);
    }
#pragma unroll
    for (int ni = 0; ni < 4; ++ni) {
      int r = wc + ni * 16 + (l & 15);
      int q = (l >> 4) ^ (r & 3);
      bfr[ni] = __builtin_bit_cast(bf16x8, *(const us8*)&Bs[r * 32 + q * 8]);
    }
#pragma unroll
    for (int mi = 0; mi < 4; ++mi)
#pragma unroll
      for (int ni = 0; ni < 4; ++ni) acc[mi][ni] = MFMA(af[mi], bfr[ni], acc[mi][ni]);
  }
#pragma unroll
  for (int mi = 0; mi < 4; ++mi)
#pragma unroll
    for (int ni = 0; ni < 4; ++ni)
#pragma unroll
      for (int r4 = 0; r4 < 4; ++r4) {
        int row = m0 + wr + mi * 16 + (l >> 4) * 4 + r4;    // b*512 + t
        int rr = ((row & 511) << 5) + (row >> 9);           // t*32 + b
        int col = n0 + wc + ni * 16 + (l & 15);
        C[(size_t)rr * 3072 + col] = f2bf(acc[mi][ni][r4]);
      }
}

// --------------------------- persistent LSTM layer -------------------------
// 128 WGs = 8 groups (dir d = grp&1, batch-quarter q = grp>>1) x 16 members.
// Member m owns hidden units m*32..m*32+31 (all 5 gates), weights in regs.
// h exchange: 16B atomic chunks {h[6] bf16 | seq} via sc0/sc1 — 1-RTT.
__global__ __launch_bounds__(256, 1) void k_persist(
    const unsigned short* __restrict__ px,    // [2][512*32][3072] bf16 t-major
    const unsigned short* __restrict__ wp,    // this layer's packed Wh (2 dirs)
    const float* __restrict__ bias_f, const float* __restrict__ bias_b,
    char* __restrict__ hxc,                   // [2][8][16][8][6] x 16B
    unsigned short* __restrict__ ybf,         // layer0: a1bf, else null
    float* __restrict__ yf,                   // layer1: d_out, else null
    float* __restrict__ finals,               // d_out + 16777216
    int layer) {
  __shared__ float part[4][8][80];            // 10 KiB partial ps
  int wg = blockIdx.x;
  int grp = wg >> 4, m = wg & 15;
  int d = grp & 1, q = grp >> 1;
  int tid = threadIdx.x;
  int w = tid >> 6, l = tid & 63;
  int kh = w >> 1, nh = w & 1;
  int ns = m * 2 + nh;                        // 16-hidden slice id (0..31)
  const unsigned short* wpd = wp + (size_t)d * 1310720;
  const unsigned short* pxd = px + (size_t)d * 16384 * 3072;
  const float* bias = d ? bias_b : bias_f;

  // ---- Wh fragments in regs: wf[gate][kk] over this wave's K-half ----
  bf16x8 wf[5][8];
#pragma unroll
  for (int g5 = 0; g5 < 5; ++g5)
#pragma unroll
    for (int kk = 0; kk < 8; ++kk)
      wf[g5][kk] = __builtin_bit_cast(
          bf16x8,
          *(const us8*)&wpd[(size_t)((g5 * 32 + ns) * 16 + kh * 8 + kk) * 512 + l * 8]);

  // ---- epilogue constants: 1 output (row r, hidden jg) per thread ----
  int r = tid >> 5, j = tid & 31, jg = m * 32 + j, b = q * 8 + r;
  float bv[5];
#pragma unroll
  for (int g5 = 0; g5 < 5; ++g5) bv[g5] = bias[(g5 << 9) + jg];

  float c = 0.f;
  unsigned short xv[6];
  {
    int t0 = d ? 511 : 0;
    const unsigned short* pp = pxd + ((size_t)((t0 << 5) + b)) * 3072 + jg;
#pragma unroll
    for (int q6 = 0; q6 < 6; ++q6) xv[q6] = pp[q6 << 9];
  }

  // ---- chunk-exchange addressing ----
  int sel = l >> 4;                           // 0..3 -> frag col-octet
  int p0 = (sel == 1) ? 1 : (sel == 2) ? 2 : (sel == 3) ? 4 : 0;
  bool s1 = (sel == 1), s2 = (sel == 2);
  int lrow = l & 15;                          // frag row (valid < 8)
  int row8 = l & 7;
  char* hxg = hxc + (size_t)grp * 12288;      // + buf*98304
  int coff[8];
#pragma unroll
  for (int kk = 0; kk < 8; ++kk)
    coff[kk] = (((kh * 8 + kk) * 8 + row8) * 6 + p0) * 16;
  int myc = l & 31;                           // publish chunk id (valid < 6)
  int pbase = l & 32;                         // publish shfl base lane
  int prow = 2 * w + (l >> 5);                // publish row

  for (int s = 0; s < 512; ++s) {
    int t = d ? (511 - s) : s;
    char* cbase = hxg + (size_t)(s & 1) * 98304;

    // ---- poll-on-data: load chunks until seq == s (payload rides along) ----
    u32x4 ca[8], cb2[8];
    {
      unsigned int tgt = (unsigned int)s;
      long guard = 0;
      bool ok;
      do {
        if (lrow < 8) {
#pragma unroll
          for (int kk = 0; kk < 8; ++kk)
            chunk2_load(cbase + coff[kk], ca[kk], cb2[kk]);
        }
        asm volatile("s_waitcnt vmcnt(0)" ::: "memory");
        bool mine = true;
        if (lrow < 8) {
#pragma unroll
          for (int kk = 0; kk < 8; ++kk)
            mine = mine && (ca[kk][3] == tgt) && (cb2[kk][3] == tgt);
        }
        ok = (__all((int)mine) != 0);
      } while (!ok && ++guard < 50000);
    }

    // ---- assemble A-fragments (dword-aligned picks) + MFMA ----
    f32x4 acc[5];
#pragma unroll
    for (int g5 = 0; g5 < 5; ++g5) acc[g5] = (f32x4){0.f, 0.f, 0.f, 0.f};
#pragma unroll
    for (int kk = 0; kk < 8; ++kk) {
      u32x4 a = ca[kk], bb = cb2[kk], f;
      f[0] = s1 ? a[1] : (s2 ? a[2] : a[0]);
      f[1] = s1 ? a[2] : (s2 ? bb[0] : a[1]);
      f[2] = s1 ? bb[0] : (s2 ? bb[1] : a[2]);
      f[3] = s1 ? bb[1] : (s2 ? bb[2] : bb[0]);
      bf16x8 av = __builtin_bit_cast(bf16x8, f);
#pragma unroll
      for (int g5 = 0; g5 < 5; ++g5) acc[g5] = MFMA(av, wf[g5][kk], acc[g5]);
    }
    if (l < 32) {
#pragma unroll
      for (int g5 = 0; g5 < 5; ++g5)
#pragma unroll
        for (int r4 = 0; r4 < 4; ++r4)
          part[w][(l >> 4) * 4 + r4][g5 * 16 + (l & 15)] = acc[g5][r4];
    }
    __syncthreads();                          // B1: part ready

    // ---- gates / state (1 output per thread) ----
    float ht;
    {
      int nhe = j >> 4, jc = j & 15;
      float ps_[5];
#pragma unroll
      for (int g5 = 0; g5 < 5; ++g5) {
        int cc = g5 * 16 + jc;
        ps_[g5] = part[nhe][r][cc] + part[2 + nhe][r][cc] + bv[g5];
      }
      float x0 = bf2f(xv[0]), x1 = bf2f(xv[1]), x2 = bf2f(xv[2]);
      float x3 = bf2f(xv[3]), x4 = bf2f(xv[4]), x5 = bf2f(xv[5]);
      float iG = sigf(x0 + ps_[0]);
      float fG = sigf(x1 + ps_[1]);
      float gG = tanh_(x2 + ps_[2]);
      float oG = sigf(x3 + ps_[3]);
      float cn = iG * gG + fG * c;
      c = cn;
      ht = oG * tanh_(cn);
      float rG = sigf(x4 + ps_[4]);
      ht = rG * ht + (1.f - rG) * x5;
      size_t yo = ((size_t)(b * 512 + t)) * 1024 + d * 512 + jg;
      if (ybf) ybf[yo] = f2bf(ht);
      else     yf[yo] = ht;
      if (s == 511) {
        int fo = (layer * 32 + b) * 1024 + d * 512 + jg;
        finals[fo] = ht;            // final_h
        finals[65536 + fo] = cn;    // final_c
      }
    }

    if (s < 511) {
      // ---- publish h(s+1): intra-wave shfl pack, fire-and-forget 16B ----
      unsigned int hbits = (unsigned int)f2bf(ht);
      unsigned int vv[6];
#pragma unroll
      for (int i = 0; i < 6; ++i)
        vv[i] = __shfl(hbits, (pbase + myc * 6 + i) & 63);
      unsigned int pw0 = vv[0] | (vv[1] << 16);
      unsigned int pw1 = vv[2] | (vv[3] << 16);
      unsigned int pw2 = vv[4] | (vv[5] << 16);
      if (myc == 5) { pw1 = 0; pw2 = 0; }
      if (myc < 6) {
        char* dst = hxg + (size_t)((s + 1) & 1) * 98304 +
                    (size_t)(((m * 8 + prow) * 6 + myc)) * 16;
        u32x4 pv = {pw0, pw1, pw2, (unsigned int)(s + 1)};
        hstore16(dst, pv);
      }
      // ---- px prefetch for s+1 (no vmcnt waits on it until next poll) ----
      int tn = d ? (511 - (s + 1)) : (s + 1);
      const unsigned short* pp = pxd + ((size_t)((tn << 5) + b)) * 3072 + jg;
#pragma unroll
      for (int q6 = 0; q6 < 6; ++q6) xv[q6] = pp[q6 << 9];
    }
    __syncthreads();                          // B2: part-readers done
  }
}

// --------------------------- host ------------------------------------------

extern "C" void kernel_launch(void* const* d_in, const int* in_sizes, int n_in,
                              void* d_out, int out_size, void* d_ws, size_t ws_size,
                              hipStream_t stream) {
  (void)in_sizes; (void)n_in; (void)out_size; (void)ws_size;
  const float* x = (const float*)d_in[0];
  const float* Wx[4] = {(const float*)d_in[1], (const float*)d_in[4],
                        (const float*)d_in[7], (const float*)d_in[10]};
  const float* Wh[4] = {(const float*)d_in[2], (const float*)d_in[5],
                        (const float*)d_in[8], (const float*)d_in[11]};
  const float* bs[4] = {(const float*)d_in[3], (const float*)d_in[6],
                        (const float*)d_in[9], (const float*)d_in[12]};

  // ws: px + packed Wh + chunk exchange (~202.2 MiB)
  char* ws = (char*)d_ws;
  unsigned short* px   = (unsigned short*)(ws);
  unsigned short* whp  = (unsigned short*)(ws + 201326592);
  char*           hxc  = (char*)(ws + 211812352);

  // d_out doubles as scratch for transients (all dead before final y writes)
  char* ob = (char*)d_out;
  unsigned short* xbf  = (unsigned short*)(ob);             // 16 MiB, phase A
  unsigned short* wxt0 = (unsigned short*)(ob + 16777216);  // 6 MiB, phase A
  unsigned short* wxt1 = (unsigned short*)(ob + 33554432);  // 12 MiB
  unsigned short* a1bf = (unsigned short*)(ob);             // 32 MiB, phase B
  float* out = (float*)d_out;
  float* finals = out + 16777216;

  k_convert_x<<<8192, 256, 0, stream>>>(x, xbf, 2097152);
  k_pack_wxT<<<dim3(96, 32, 4), 256, 0, stream>>>(Wx[0], Wx[1], Wx[2], Wx[3], wxt0, wxt1);
  k_pack_whp<<<dim3(640, 4), 256, 0, stream>>>(Wh[0], Wh[1], Wh[2], Wh[3], whp);

  for (int layer = 0; layer < 2; ++layer) {
    int K = layer ? 1024 : 512;
    const unsigned short* Ag = layer ? a1bf : xbf;
    const unsigned short* wxt = layer ? wxt1 : wxt0;
    k_gemm<<<dim3(128, 24, 2), 256, 0, stream>>>(Ag, wxt, px, K);
    hipMemsetAsync(hxc, 0, 196608, stream);   // seq=0 == initial h state
    k_persist<<<128, 256, 0, stream>>>(
        px, whp + (size_t)layer * 2621440, bs[layer * 2], bs[layer * 2 + 1],
        hxc, layer ? nullptr : a1bf, layer ? out : nullptr, finals, layer);
  }
}